// Round 2
// baseline (2325.186 us; speedup 1.0000x reference)
//
#include <hip/hip_runtime.h>
#include <hip/hip_bf16.h>

typedef unsigned short u16;
typedef signed char i8;
typedef __attribute__((ext_vector_type(4))) float f32x4;
typedef __attribute__((ext_vector_type(4))) int i32x4;
typedef __attribute__((ext_vector_type(8))) short bf16x8;

#define HID 256
#define NG 1024
#define TSTEPS 512
#define BATCH 256
#define CH 16          // steps per chunk
#define NCH 32         // chunks (CH*NCH = 512)
#define BB 4           // batch rows per rec block (1 cell/lane via A-row duplication)
#define HSTR 288       // h_lds row stride bytes
#define LOG2E 1.4426950408889634f
#define PRE_TSTR 262144   // per-t' element stride in pre: 64 btiles * 4 j * 1024 u * 4 kb

// fused-stage block roles
#define GB0 128        // gemm0 blocks [128,144)
#define GB1 144        // gemm1 blocks [144,176)
#define NBLK 176

#define MFMA_BF16(a, b, c) __builtin_amdgcn_mfma_f32_16x16x32_bf16((a), (b), (c), 0, 0, 0)
#define MFMA_I8(a, b, c)   __builtin_amdgcn_mfma_i32_16x16x64_i8((a), (b), (c), 0, 0, 0)

__device__ __forceinline__ float rcpf_(float x) {
#if __has_builtin(__builtin_amdgcn_rcpf)
    return __builtin_amdgcn_rcpf(x);
#else
    return 1.f / x;
#endif
}
__device__ __forceinline__ float exp2_(float x) {
#if __has_builtin(__builtin_amdgcn_exp2f)
    return __builtin_amdgcn_exp2f(x);
#else
    return exp2f(x);
#endif
}
__device__ __forceinline__ float sigm2(float y) { return rcpf_(1.f + exp2_(-y)); }
__device__ __forceinline__ float tanh2(float y2) { return fmaf(-2.f, rcpf_(exp2_(y2) + 1.f), 1.f); }
__device__ __forceinline__ u16 f2bf(float v){ __hip_bfloat16 h=__float2bfloat16(v); return __builtin_bit_cast(u16,h); }
__device__ __forceinline__ float bf2f(u16 u){ unsigned x=((unsigned)u)<<16; return __builtin_bit_cast(float,x); }

// ---------------------------------------------------------------------------
// prep_a: per-gate-row i8 scales for Whh0/Whh1 (recurrent path only); log2e
// folded into dequant scales and biases. (unchanged)
// ---------------------------------------------------------------------------
__global__ void prep_a(const float* __restrict__ Whh0, const float* __restrict__ Whh1,
                       const float* __restrict__ bih0, const float* __restrict__ bhh0,
                       const float* __restrict__ bih1, const float* __restrict__ bhh1,
                       float* __restrict__ qs0, float* __restrict__ dq0s,
                       float* __restrict__ qs1, float* __restrict__ dq1s,
                       float* __restrict__ b0s, float* __restrict__ b1s) {
    int r = blockIdx.x * blockDim.x + threadIdx.x;
    if (r >= NG) return;
    float m0 = 1e-20f, m1 = 1e-20f;
    for (int k = 0; k < HID; k++) {
        m0 = fmaxf(m0, fabsf(Whh0[r * HID + k]));
        m1 = fmaxf(m1, fabsf(Whh1[r * HID + k]));
    }
    qs0[r] = 127.f / m0;   dq0s[r] = m0 / 16129.f * LOG2E;
    qs1[r] = 127.f / m1;   dq1s[r] = m1 / 16129.f * LOG2E;
    b0s[r] = (bih0[r] + bhh0[r]) * LOG2E;
    b1s[r] = (bih1[r] + bhh1[r]) * LOG2E;
}

// ---------------------------------------------------------------------------
// prep_b: i8 frag packs for Whh0/Whh1; bf16 Wih1 frags (x LOG2E); bf16 Wih0
// frags (x LOG2E, K pad 5->32); x padded to 8 bf16/token; zeroed states.
// ---------------------------------------------------------------------------
__global__ void prep_b(const float* __restrict__ x,
    const float* __restrict__ Wih0, const float* __restrict__ Whh0,
    const float* __restrict__ Wih1, const float* __restrict__ Whh1,
    const float* __restrict__ qs0, const float* __restrict__ qs1,
    i8* __restrict__ wi80, i8* __restrict__ wi81,
    u16* __restrict__ wih1f, u16* __restrict__ wih0f,
    i8* __restrict__ hs0, i8* __restrict__ hs1,
    float* __restrict__ cs0, float* __restrict__ cs1, u16* __restrict__ xpad)
{
    const int stride = gridDim.x * blockDim.x;
    const int tid = blockIdx.x * blockDim.x + threadIdx.x;
    for (int i = tid; i < NG * HID; i += stride) {   // i8 packs (recurrent)
        int e = i & 15, l = (i >> 4) & 63, kc = (i >> 10) & 3, gt = i >> 12;
        int row = 16 * gt + (l & 15);
        int k = kc * 64 + (l >> 4) * 16 + e;
        float q0 = __builtin_rintf(Whh0[row * HID + k] * qs0[row]);
        float q1 = __builtin_rintf(Whh1[row * HID + k] * qs1[row]);
        wi80[i] = (i8)fminf(fmaxf(q0, -127.f), 127.f);
        wi81[i] = (i8)fminf(fmaxf(q1, -127.f), 127.f);
    }
    for (int i = tid; i < NG * HID; i += stride) {   // Wih1 bf16 frags, scaled
        int gt = i >> 12, kk = (i >> 9) & 7, l = (i >> 3) & 63, e = i & 7;
        wih1f[i] = f2bf(Wih1[(16 * gt + (l & 15)) * HID + kk * 32 + (l >> 4) * 8 + e] * LOG2E);
    }
    for (int i = tid; i < 32768; i += stride) {      // Wih0 bf16 frags, scaled
        int gt = i >> 9, l = (i >> 3) & 63, e = i & 7;
        int k = (l >> 4) * 8 + e;
        wih0f[i] = (k < 5) ? f2bf(Wih0[(16 * gt + (l & 15)) * 5 + k] * LOG2E) : (u16)0;
    }
    for (int i = tid; i < TSTEPS * BATCH * 8; i += stride) {  // x padded to 8, token-major
        int tok = i >> 3, k = i & 7, t = tok >> 8, b = tok & 255;
        xpad[i] = (k < 5) ? f2bf(x[((size_t)b * TSTEPS + t) * 5 + k]) : (u16)0;
    }
    for (int i = tid; i < BATCH * HID; i += stride) { hs0[i] = 0; hs1[i] = 0; cs0[i] = 0.f; cs1[i] = 0.f; }
}

// ---------------------------------------------------------------------------
// stage_fused(L): four pipeline roles on disjoint blocks (gemms overlap recs):
//   blocks [0,64):    rec layer0, chunk L-1   (reads pre0, writes h0c)
//   blocks [64,128):  rec layer1, chunk L-3   (reads pre1)
//   blocks [128,144): gemm0: pre0(chunk L)   = log2e*(Wih0 x + b0)
//   blocks [144,176): gemm1: pre1(chunk L-2) = log2e*(Wih1 h0 + b1)
//
// R1 POST-MORTEM FIX: pre layout is now BB=4-batch-tiled:
//   idx = ((t*64 + btile)*4 + j)*1024 + u*4 + kb    (gate = j*256+u, batch = btile*4+kb)
// so each rec block's per-step 8KB read is contiguous (wave reads 128B/load,
// 100% line use, zero cross-block/XCD line sharing). The old [gate][16batch]
// layout fetched every 64B line ~4x across XCDs: FETCH 38.6MB/dispatch at
// 881 GB/s = 2.7us/step = the measured stall. Bit-identical values.
// ---------------------------------------------------------------------------
__global__ __launch_bounds__(1024) __attribute__((amdgpu_waves_per_eu(4, 4)))
void stage_fused(int L,
    const u16* __restrict__ xpad8, const u16* __restrict__ wih0f, const float* __restrict__ b0s,
    const u16* __restrict__ wih1f, const float* __restrict__ b1s,
    u16* __restrict__ p0w, const u16* __restrict__ p0r,
    u16* __restrict__ h0w, const u16* __restrict__ h0r,
    u16* __restrict__ p1w, const u16* __restrict__ p1r,
    const i8* __restrict__ wi80, const i8* __restrict__ wi81,
    const float* __restrict__ dq0s, const float* __restrict__ dq1s,
    i8* __restrict__ hs0, i8* __restrict__ hs1,
    float* __restrict__ cs0, float* __restrict__ cs1)
{
    __shared__ i8 h_lds[2][BB * HSTR];
    const int bid = blockIdx.x;
    const int tid = threadIdx.x, lane = tid & 63;
    const int col = lane & 15, kgrp = lane >> 4;

    if (bid < GB0) {
        // ---------------- recurrent role ----------------
        const int layer = bid >> 6;
        if (layer == 0) { if (L < 1 || L > NCH) return; }
        else            { if (L < 3 || L > NCH + 2) return; }
        const int btile = bid & 63;
        const u16* pre   = layer ? p1r : p0r;
        const i8*  wi8   = layer ? wi81 : wi80;
        const float* dq  = layer ? dq1s : dq0s;
        i8*    h_state   = layer ? hs1 : hs0;
        float* c_state   = layer ? cs1 : cs0;
        const int w = tid >> 6;
        const int b0 = btile * BB;
        const int u = w * 16 + col;          // h-unit this lane owns

        float sc[4];
        i32x4 wv[4][4];                      // 64 VGPRs resident weights
#pragma unroll
        for (int j = 0; j < 4; j++) {
            const int gt = 16 * j + w;
            sc[j] = dq[gt * 16 + col];
#pragma unroll
            for (int kc = 0; kc < 4; kc++)
                wv[j][kc] = ((const i32x4*)wi8)[(gt * 4 + kc) * 64 + lane];
        }
        if (tid < 64 * BB) {
            const int rrow = tid >> 6, cc = (tid & 63) * 4;
            *(int*)&h_lds[0][rrow * HSTR + cc] = *(const int*)&h_state[(b0 + rrow) * HID + cc];
        }
        float c_reg = c_state[(size_t)(b0 + kgrp) * HID + u];

        // pre base for this lane: btile*4096 + u*4 + kgrp   (contiguous per wave)
        const u16* pb = pre + ((size_t)btile << 12) + (u << 2) + kgrp;
        u16 pvA[4], pvB[4];
#pragma unroll
        for (int j = 0; j < 4; j++) pvA[j] = pb[j << 10];
        __syncthreads();

// One LSTM step. CUR literal (0/1). PVC: this step's pre (in flight since
// last step). PVN: next step's pre, issued before the barrier and left in
// flight across it (barrier drains only lgkmcnt).
#define REC_STEP(T, CUR, PVC, PVN) do {                                             \
        _Pragma("unroll")                                                           \
        for (int j = 0; j < 4; j++)                                                 \
            asm volatile("" : "+v"(wv[j][0]), "+v"(wv[j][1]),                       \
                              "+v"(wv[j][2]), "+v"(wv[j][3]));                      \
        i32x4 acc[4];                                                               \
        _Pragma("unroll")                                                           \
        for (int j = 0; j < 4; j++) acc[j] = (i32x4){0, 0, 0, 0};                   \
        _Pragma("unroll")                                                           \
        for (int kc = 0; kc < 4; kc++) {                                            \
            i32x4 a_ = *(const i32x4*)&h_lds[CUR][(col >> 2) * HSTR + kc * 64 + kgrp * 16]; \
            _Pragma("unroll")                                                       \
            for (int j = 0; j < 4; j++) acc[j] = MFMA_I8(a_, wv[j][kc], acc[j]);    \
        }                                                                           \
        const int tn_ = ((T) + 1 < CH) ? (T) + 1 : (T);                             \
        _Pragma("unroll")                                                           \
        for (int j = 0; j < 4; j++) PVN[j] = pb[(size_t)tn_ * PRE_TSTR + (j << 10)];\
        const float yi = fmaf((float)acc[0][0], sc[0], bf2f(PVC[0]));               \
        const float yf = fmaf((float)acc[1][0], sc[1], bf2f(PVC[1]));               \
        const float yg = fmaf((float)acc[2][0], sc[2], bf2f(PVC[2]));               \
        const float yo = fmaf((float)acc[3][0], sc[3], bf2f(PVC[3]));               \
        const float iv = sigm2(yi), fv = sigm2(yf), ov = sigm2(yo);                 \
        const float gv = tanh2(yg + yg);                                            \
        const float cn = fmaf(fv, c_reg, iv * gv);                                  \
        c_reg = cn;                                                                 \
        const float hv = ov * tanh2(cn * (2.f * LOG2E));                            \
        h_lds[(CUR) ^ 1][kgrp * HSTR + u] = (i8)__float2int_rn(hv * 127.f);         \
        if (layer == 0)                                                             \
            h0w[((size_t)(T) * BATCH + b0 + kgrp) * HID + u] = f2bf(hv);            \
        asm volatile("s_waitcnt lgkmcnt(0)" ::: "memory");                          \
        __builtin_amdgcn_s_barrier();                                               \
        __builtin_amdgcn_sched_barrier(0);                                          \
    } while (0)

#pragma unroll 1
        for (int t2 = 0; t2 < CH; t2 += 2) {
            REC_STEP(t2,     0, pvA, pvB);
            REC_STEP(t2 + 1, 1, pvB, pvA);
        }
#undef REC_STEP

        c_state[(size_t)(b0 + kgrp) * HID + u] = c_reg;
        if (tid < 64 * BB) {
            const int rrow = tid >> 6, cc = (tid & 63) * 4;
            *(int*)&h_state[(b0 + rrow) * HID + cc] = *(const int*)&h_lds[0][rrow * HSTR + cc];
        }
        return;
    } else if (bid < GB1) {
        // ---------------- gemm0: pre0(chunk L) ----------------
        if (L >= NCH) return;
        const int tp = bid - GB0;            // t' within chunk, 0..15
        const int w16 = tid >> 6;
        const int gq = w16 >> 2, w = w16 & 3;   // gq = j (gate>>8) for all this wave's tiles
        int gts[4];
#pragma unroll
        for (int tm = 0; tm < 4; tm++) gts[tm] = gq * 16 + w * 4 + tm;
        f32x4 brow[4];
        bf16x8 wv4[4];
#pragma unroll
        for (int tm = 0; tm < 4; tm++) {
            brow[tm] = *(const f32x4*)&b0s[gts[tm] * 16 + kgrp * 4];
            wv4[tm] = *(const bf16x8*)&wih0f[((size_t)gts[tm] * 64 + lane) * 8];
        }
        const u16* Ab = xpad8 + ((size_t)L * CH + tp) * BATCH * 8;
#pragma unroll 1
        for (int bt = 0; bt < 16; bt++) {
            bf16x8 af = {0, 0, 0, 0, 0, 0, 0, 0};   // K beyond 8 is zero-padded
            if (kgrp == 0) af = *(const bf16x8*)&Ab[(bt * 16 + col) * 8];
            f32x4 acc[4];
#pragma unroll
            for (int tm = 0; tm < 4; tm++) acc[tm] = brow[tm];
#pragma unroll
            for (int tm = 0; tm < 4; tm++) acc[tm] = MFMA_BF16(wv4[tm], af, acc[tm]);
            // store: batch b = bt*16+col -> (btile=b>>2, kb=b&3); gate -> (j=gq, uu)
            const size_t bbase = (((size_t)tp * 64 + bt * 4 + (col >> 2)) * 4 + gq) << 10;
#pragma unroll
            for (int tm = 0; tm < 4; tm++)
#pragma unroll
                for (int rr = 0; rr < 4; rr++) {
                    const int uu = (w * 4 + tm) * 16 + kgrp * 4 + rr;
                    p0w[bbase + (uu << 2) + (col & 3)] = f2bf(acc[tm][rr]);
                }
        }
        return;
    } else {
        // ---------------- gemm1: pre1(chunk L-2) ----------------
        if (L < 2 || L > NCH + 1) return;
        const int g = bid - GB1;             // 0..31
        const int tp = g >> 1, gqq = g & 1;
        const int w16 = tid >> 6;
        const int gq = gqq * 2 + (w16 >> 3), w8 = w16 & 7;
        int gts[2];
#pragma unroll
        for (int tm = 0; tm < 2; tm++) gts[tm] = gq * 16 + w8 * 2 + tm;
        f32x4 brow[2];
        bf16x8 wv8[2][8];                    // 64 VGPRs resident weights
#pragma unroll
        for (int tm = 0; tm < 2; tm++) {
            brow[tm] = *(const f32x4*)&b1s[gts[tm] * 16 + kgrp * 4];
#pragma unroll
            for (int kk = 0; kk < 8; kk++)
                wv8[tm][kk] = *(const bf16x8*)&wih1f[((size_t)(gts[tm] * 8 + kk) * 64 + lane) * 8];
        }
#pragma unroll 1
        for (int bt = 0; bt < 16; bt++) {
            f32x4 acc[2];
#pragma unroll
            for (int tm = 0; tm < 2; tm++) acc[tm] = brow[tm];
#pragma unroll
            for (int kk = 0; kk < 8; kk++) {
                bf16x8 a_ = *(const bf16x8*)&h0r[((size_t)tp * BATCH + bt * 16 + col) * HID + kk * 32 + kgrp * 8];
#pragma unroll
                for (int tm = 0; tm < 2; tm++) acc[tm] = MFMA_BF16(wv8[tm][kk], a_, acc[tm]);
            }
            const size_t bbase = (((size_t)tp * 64 + bt * 4 + (col >> 2)) * 4 + gq) << 10;
#pragma unroll
            for (int tm = 0; tm < 2; tm++)
#pragma unroll
                for (int rr = 0; rr < 4; rr++) {
                    const int uu = (w8 * 2 + tm) * 16 + kgrp * 4 + rr;
                    p1w[bbase + (uu << 2) + (col & 3)] = f2bf(acc[tm][rr]);
                }
        }
        return;
    }
}

// ---------------------------------------------------------------------------
// head: y = sigmoid(relu(h_last) @ Wh^T + bh)
// ---------------------------------------------------------------------------
__global__ void head_kernel(const i8* __restrict__ hs1,
                            const float* __restrict__ Wh, const float* __restrict__ bh,
                            float* __restrict__ y) {
    int b = blockIdx.x;
    int l = threadIdx.x;
    const float inv127 = 1.f / 127.f;
    float hr[4];
#pragma unroll
    for (int i = 0; i < 4; ++i) hr[i] = fmaxf((float)hs1[b * HID + l + 64 * i] * inv127, 0.f);
    for (int o = 0; o < 3; ++o) {
        float s = 0.f;
#pragma unroll
        for (int i = 0; i < 4; ++i) s += hr[i] * Wh[o * HID + l + 64 * i];
        for (int off = 32; off > 0; off >>= 1) s += __shfl_down(s, off, 64);
        if (l == 0) y[b * 3 + o] = 1.f / (1.f + exp2_(-(s + bh[o]) * LOG2E));
    }
}

extern "C" void kernel_launch(void* const* d_in, const int* in_sizes, int n_in,
                              void* d_out, int out_size, void* d_ws, size_t ws_size,
                              hipStream_t stream) {
    const float* x    = (const float*)d_in[0];
    const float* Wih0 = (const float*)d_in[1];
    const float* Whh0 = (const float*)d_in[2];
    const float* bih0 = (const float*)d_in[3];
    const float* bhh0 = (const float*)d_in[4];
    const float* Wih1 = (const float*)d_in[5];
    const float* Whh1 = (const float*)d_in[6];
    const float* bih1 = (const float*)d_in[7];
    const float* bhh1 = (const float*)d_in[8];
    const float* Wh   = (const float*)d_in[9];
    const float* bh   = (const float*)d_in[10];

    char* ws = (char*)d_ws;
    i8*    wi80  = (i8*)(ws);                            // 256 KB
    i8*    wi81  = (i8*)(ws + ((size_t)256 << 10));      // 256 KB
    u16*   wih1f = (u16*)(ws + ((size_t)512 << 10));     // 512 KB
    u16*   wih0f = (u16*)(ws + ((size_t)1024 << 10));    // 64 KB
    float* qs0   = (float*)(ws + ((size_t)1088 << 10));
    float* dq0s  = (float*)(ws + ((size_t)1092 << 10));
    float* qs1   = (float*)(ws + ((size_t)1096 << 10));
    float* dq1s  = (float*)(ws + ((size_t)1100 << 10));
    float* b0s   = (float*)(ws + ((size_t)1104 << 10));
    float* b1s   = (float*)(ws + ((size_t)1108 << 10));
    i8*    hs0   = (i8*)(ws + ((size_t)1112 << 10));     // 64 KB
    i8*    hs1   = (i8*)(ws + ((size_t)1176 << 10));     // 64 KB
    float* cs0   = (float*)(ws + ((size_t)1240 << 10));  // 256 KB
    float* cs1   = (float*)(ws + ((size_t)1496 << 10));  // 256 KB
    u16*   xpad  = (u16*)(ws + ((size_t)1752 << 10));    // 2 MB  [tok][8] bf16
    u16*   h0c   = (u16*)(ws + ((size_t)3800 << 10));    // 2 x 2 MB (chunk parity)
    u16*   pre0  = (u16*)(ws + ((size_t)7896 << 10));    // 2 x 8 MB (chunk parity)
    u16*   pre1  = (u16*)(ws + ((size_t)24280 << 10));   // 2 x 8 MB -> total ~39.7 MB
    const size_t PRE_ELE = (size_t)CH * BATCH * NG;      // 4 Mi elements (8 MB)
    const size_t H0C_ELE = (size_t)CH * BATCH * HID;     // 1 Mi elements (2 MB)

    prep_a<<<4, 256, 0, stream>>>(Whh0, Whh1, bih0, bhh0, bih1, bhh1,
                                  qs0, dq0s, qs1, dq1s, b0s, b1s);
    prep_b<<<1024, 256, 0, stream>>>(x, Wih0, Whh0, Wih1, Whh1, qs0, qs1,
                                     wi80, wi81, wih1f, wih0f, hs0, hs1, cs0, cs1, xpad);
    // pipeline: gemm0(c=L) | rec0(c=L-1) | gemm1(c=L-2) | rec1(c=L-3)
    for (int L = 0; L <= NCH + 2; L++) {
        const size_t pA = (size_t)(L & 1), pB = pA ^ 1;
        stage_fused<<<NBLK, 1024, 0, stream>>>(L, xpad, wih0f, b0s, wih1f, b1s,
            pre0 + pA * PRE_ELE,        // gemm0 writes chunk L      (parity L)
            pre0 + pB * PRE_ELE,        // rec0 reads chunk L-1      (parity L-1)
            h0c  + pB * H0C_ELE,        // rec0 writes chunk L-1
            h0c  + pA * H0C_ELE,        // gemm1 reads chunk L-2     (parity L)
            pre1 + pA * PRE_ELE,        // gemm1 writes chunk L-2
            pre1 + pB * PRE_ELE,        // rec1 reads chunk L-3      (parity L-1)
            wi80, wi81, dq0s, dq1s, hs0, hs1, cs0, cs1);
    }
    head_kernel<<<BATCH, 64, 0, stream>>>(hs1, Wh, bh, (float*)d_out);
}

// Round 3
// 1989.095 us; speedup vs baseline: 1.1690x; 1.1690x over previous
//
#include <hip/hip_runtime.h>
#include <hip/hip_bf16.h>

typedef unsigned short u16;
typedef signed char i8;
typedef __attribute__((ext_vector_type(4))) float f32x4;
typedef __attribute__((ext_vector_type(4))) int i32x4;
typedef __attribute__((ext_vector_type(8))) short bf16x8;
typedef __attribute__((ext_vector_type(2))) unsigned int u32x2;

#define HID 256
#define NG 1024
#define TSTEPS 512
#define BATCH 256
#define CH 16          // steps per chunk
#define NCH 32         // chunks (CH*NCH = 512)
#define BB 4           // batch rows per rec block (1 cell/lane via A-row duplication)
#define HSTR 288       // h_lds row stride bytes
#define LOG2E 1.4426950408889634f
#define PRE_TSTR 262144   // per-t' element stride in pre: 64 btiles * 4 j * 1024 (u*4+kb)

// fused-stage block roles
#define GB0 128        // gemm0 blocks [128,160)
#define GB1 160        // gemm1 blocks [160,224)
#define NBLK 224

#define MFMA_BF16(a, b, c) __builtin_amdgcn_mfma_f32_16x16x32_bf16((a), (b), (c), 0, 0, 0)
#define MFMA_I8(a, b, c)   __builtin_amdgcn_mfma_i32_16x16x64_i8((a), (b), (c), 0, 0, 0)

__device__ __forceinline__ float rcpf_(float x) {
#if __has_builtin(__builtin_amdgcn_rcpf)
    return __builtin_amdgcn_rcpf(x);
#else
    return 1.f / x;
#endif
}
__device__ __forceinline__ float exp2_(float x) {
#if __has_builtin(__builtin_amdgcn_exp2f)
    return __builtin_amdgcn_exp2f(x);
#else
    return exp2f(x);
#endif
}
__device__ __forceinline__ float sigm2(float y) { return rcpf_(1.f + exp2_(-y)); }
__device__ __forceinline__ float tanh2(float y2) { return fmaf(-2.f, rcpf_(exp2_(y2) + 1.f), 1.f); }
__device__ __forceinline__ u16 f2bf(float v){ __hip_bfloat16 h=__float2bfloat16(v); return __builtin_bit_cast(u16,h); }
__device__ __forceinline__ float bf2f(u16 u){ unsigned x=((unsigned)u)<<16; return __builtin_bit_cast(float,x); }

// ---------------------------------------------------------------------------
// prep_a: per-gate-row i8 scales for Whh0/Whh1; log2e folded into dequant
// scales and biases. (unchanged)
// ---------------------------------------------------------------------------
__global__ void prep_a(const float* __restrict__ Whh0, const float* __restrict__ Whh1,
                       const float* __restrict__ bih0, const float* __restrict__ bhh0,
                       const float* __restrict__ bih1, const float* __restrict__ bhh1,
                       float* __restrict__ qs0, float* __restrict__ dq0s,
                       float* __restrict__ qs1, float* __restrict__ dq1s,
                       float* __restrict__ b0s, float* __restrict__ b1s) {
    int r = blockIdx.x * blockDim.x + threadIdx.x;
    if (r >= NG) return;
    float m0 = 1e-20f, m1 = 1e-20f;
    for (int k = 0; k < HID; k++) {
        m0 = fmaxf(m0, fabsf(Whh0[r * HID + k]));
        m1 = fmaxf(m1, fabsf(Whh1[r * HID + k]));
    }
    qs0[r] = 127.f / m0;   dq0s[r] = m0 / 16129.f * LOG2E;
    qs1[r] = 127.f / m1;   dq1s[r] = m1 / 16129.f * LOG2E;
    b0s[r] = (bih0[r] + bhh0[r]) * LOG2E;
    b1s[r] = (bih1[r] + bhh1[r]) * LOG2E;
}

// ---------------------------------------------------------------------------
// prep_b: i8 frag packs for Whh0/Whh1; bf16 Wih1 frags (x LOG2E); bf16 Wih0
// frags (x LOG2E, K pad 5->32); x padded to 8 bf16/token; zeroed states.
// (unchanged)
// ---------------------------------------------------------------------------
__global__ void prep_b(const float* __restrict__ x,
    const float* __restrict__ Wih0, const float* __restrict__ Whh0,
    const float* __restrict__ Wih1, const float* __restrict__ Whh1,
    const float* __restrict__ qs0, const float* __restrict__ qs1,
    i8* __restrict__ wi80, i8* __restrict__ wi81,
    u16* __restrict__ wih1f, u16* __restrict__ wih0f,
    i8* __restrict__ hs0, i8* __restrict__ hs1,
    float* __restrict__ cs0, float* __restrict__ cs1, u16* __restrict__ xpad)
{
    const int stride = gridDim.x * blockDim.x;
    const int tid = blockIdx.x * blockDim.x + threadIdx.x;
    for (int i = tid; i < NG * HID; i += stride) {   // i8 packs (recurrent)
        int e = i & 15, l = (i >> 4) & 63, kc = (i >> 10) & 3, gt = i >> 12;
        int row = 16 * gt + (l & 15);
        int k = kc * 64 + (l >> 4) * 16 + e;
        float q0 = __builtin_rintf(Whh0[row * HID + k] * qs0[row]);
        float q1 = __builtin_rintf(Whh1[row * HID + k] * qs1[row]);
        wi80[i] = (i8)fminf(fmaxf(q0, -127.f), 127.f);
        wi81[i] = (i8)fminf(fmaxf(q1, -127.f), 127.f);
    }
    for (int i = tid; i < NG * HID; i += stride) {   // Wih1 bf16 frags, scaled
        int gt = i >> 12, kk = (i >> 9) & 7, l = (i >> 3) & 63, e = i & 7;
        wih1f[i] = f2bf(Wih1[(16 * gt + (l & 15)) * HID + kk * 32 + (l >> 4) * 8 + e] * LOG2E);
    }
    for (int i = tid; i < 32768; i += stride) {      // Wih0 bf16 frags, scaled
        int gt = i >> 9, l = (i >> 3) & 63, e = i & 7;
        int k = (l >> 4) * 8 + e;
        wih0f[i] = (k < 5) ? f2bf(Wih0[(16 * gt + (l & 15)) * 5 + k] * LOG2E) : (u16)0;
    }
    for (int i = tid; i < TSTEPS * BATCH * 8; i += stride) {  // x padded to 8, token-major
        int tok = i >> 3, k = i & 7, t = tok >> 8, b = tok & 255;
        xpad[i] = (k < 5) ? f2bf(x[((size_t)b * TSTEPS + t) * 5 + k]) : (u16)0;
    }
    for (int i = tid; i < BATCH * HID; i += stride) { hs0[i] = 0; hs1[i] = 0; cs0[i] = 0.f; cs1[i] = 0.f; }
}

// ---------------------------------------------------------------------------
// stage_fused(L): four pipeline roles on disjoint blocks (gemms overlap recs):
//   blocks [0,64):    rec layer0, chunk L-1   (reads pre0, writes h0c)
//   blocks [64,128):  rec layer1, chunk L-3   (reads pre1)
//   blocks [128,160): gemm0: pre0(chunk L)   = log2e*(Wih0 x + b0)
//   blocks [160,224): gemm1: pre1(chunk L-2) = log2e*(Wih1 h0 + b1)
//
// R2 POST-MORTEM FIX: the ~66us gate was gemm store-transaction issue: with
// mfma(W, act) the C-frag had batch on col, so pre-layout stores scattered 64
// lanes into ~16x8B segments (~16 transactions/instr; gemm0 = 65K trans/CU
// ~ 55us on 16 CUs). Swapping to mfma(act, W) transposes C: batch -> row
// (kgrp*4+rr), gate -> col. Same fragment data (A/B frag layouts identical),
// bias now per-col (same values => bit-identical). Each lane's 4 rr accs are
// 4 CONSECUTIVE pre elements (kb=rr) -> one 8B dwordx2 store; a store instr
// = 4 x 128B contiguous segments. Also gemm0 16->32 blocks, gemm1 32->64.
// ---------------------------------------------------------------------------
__global__ __launch_bounds__(1024) __attribute__((amdgpu_waves_per_eu(4, 4)))
void stage_fused(int L,
    const u16* __restrict__ xpad8, const u16* __restrict__ wih0f, const float* __restrict__ b0s,
    const u16* __restrict__ wih1f, const float* __restrict__ b1s,
    u16* __restrict__ p0w, const u16* __restrict__ p0r,
    u16* __restrict__ h0w, const u16* __restrict__ h0r,
    u16* __restrict__ p1w, const u16* __restrict__ p1r,
    const i8* __restrict__ wi80, const i8* __restrict__ wi81,
    const float* __restrict__ dq0s, const float* __restrict__ dq1s,
    i8* __restrict__ hs0, i8* __restrict__ hs1,
    float* __restrict__ cs0, float* __restrict__ cs1)
{
    __shared__ i8 h_lds[2][BB * HSTR];
    const int bid = blockIdx.x;
    const int tid = threadIdx.x, lane = tid & 63;
    const int col = lane & 15, kgrp = lane >> 4;

    if (bid < GB0) {
        // ---------------- recurrent role (unchanged) ----------------
        const int layer = bid >> 6;
        if (layer == 0) { if (L < 1 || L > NCH) return; }
        else            { if (L < 3 || L > NCH + 2) return; }
        const int btile = bid & 63;
        const u16* pre   = layer ? p1r : p0r;
        const i8*  wi8   = layer ? wi81 : wi80;
        const float* dq  = layer ? dq1s : dq0s;
        i8*    h_state   = layer ? hs1 : hs0;
        float* c_state   = layer ? cs1 : cs0;
        const int w = tid >> 6;
        const int b0 = btile * BB;
        const int u = w * 16 + col;          // h-unit this lane owns

        float sc[4];
        i32x4 wv[4][4];                      // 64 VGPRs resident weights
#pragma unroll
        for (int j = 0; j < 4; j++) {
            const int gt = 16 * j + w;
            sc[j] = dq[gt * 16 + col];
#pragma unroll
            for (int kc = 0; kc < 4; kc++)
                wv[j][kc] = ((const i32x4*)wi8)[(gt * 4 + kc) * 64 + lane];
        }
        if (tid < 64 * BB) {
            const int rrow = tid >> 6, cc = (tid & 63) * 4;
            *(int*)&h_lds[0][rrow * HSTR + cc] = *(const int*)&h_state[(b0 + rrow) * HID + cc];
        }
        float c_reg = c_state[(size_t)(b0 + kgrp) * HID + u];

        // pre base for this lane: btile*4096 + u*4 + kgrp   (contiguous per wave)
        const u16* pb = pre + ((size_t)btile << 12) + (u << 2) + kgrp;
        u16 pvA[4], pvB[4];
#pragma unroll
        for (int j = 0; j < 4; j++) pvA[j] = pb[j << 10];
        __syncthreads();

#define REC_STEP(T, CUR, PVC, PVN) do {                                             \
        _Pragma("unroll")                                                           \
        for (int j = 0; j < 4; j++)                                                 \
            asm volatile("" : "+v"(wv[j][0]), "+v"(wv[j][1]),                       \
                              "+v"(wv[j][2]), "+v"(wv[j][3]));                      \
        i32x4 acc[4];                                                               \
        _Pragma("unroll")                                                           \
        for (int j = 0; j < 4; j++) acc[j] = (i32x4){0, 0, 0, 0};                   \
        _Pragma("unroll")                                                           \
        for (int kc = 0; kc < 4; kc++) {                                            \
            i32x4 a_ = *(const i32x4*)&h_lds[CUR][(col >> 2) * HSTR + kc * 64 + kgrp * 16]; \
            _Pragma("unroll")                                                       \
            for (int j = 0; j < 4; j++) acc[j] = MFMA_I8(a_, wv[j][kc], acc[j]);    \
        }                                                                           \
        const int tn_ = ((T) + 1 < CH) ? (T) + 1 : (T);                             \
        _Pragma("unroll")                                                           \
        for (int j = 0; j < 4; j++) PVN[j] = pb[(size_t)tn_ * PRE_TSTR + (j << 10)];\
        const float yi = fmaf((float)acc[0][0], sc[0], bf2f(PVC[0]));               \
        const float yf = fmaf((float)acc[1][0], sc[1], bf2f(PVC[1]));               \
        const float yg = fmaf((float)acc[2][0], sc[2], bf2f(PVC[2]));               \
        const float yo = fmaf((float)acc[3][0], sc[3], bf2f(PVC[3]));               \
        const float iv = sigm2(yi), fv = sigm2(yf), ov = sigm2(yo);                 \
        const float gv = tanh2(yg + yg);                                            \
        const float cn = fmaf(fv, c_reg, iv * gv);                                  \
        c_reg = cn;                                                                 \
        const float hv = ov * tanh2(cn * (2.f * LOG2E));                            \
        h_lds[(CUR) ^ 1][kgrp * HSTR + u] = (i8)__float2int_rn(hv * 127.f);         \
        if (layer == 0)                                                             \
            h0w[((size_t)(T) * BATCH + b0 + kgrp) * HID + u] = f2bf(hv);            \
        asm volatile("s_waitcnt lgkmcnt(0)" ::: "memory");                          \
        __builtin_amdgcn_s_barrier();                                               \
        __builtin_amdgcn_sched_barrier(0);                                          \
    } while (0)

#pragma unroll 1
        for (int t2 = 0; t2 < CH; t2 += 2) {
            REC_STEP(t2,     0, pvA, pvB);
            REC_STEP(t2 + 1, 1, pvB, pvA);
        }
#undef REC_STEP

        c_state[(size_t)(b0 + kgrp) * HID + u] = c_reg;
        if (tid < 64 * BB) {
            const int rrow = tid >> 6, cc = (tid & 63) * 4;
            *(int*)&h_state[(b0 + rrow) * HID + cc] = *(const int*)&h_lds[0][rrow * HSTR + cc];
        }
        return;
    } else if (bid < GB1) {
        // ---------------- gemm0: pre0(chunk L), operand-swapped ----------------
        if (L >= NCH) return;
        const int g = bid - GB0;             // 0..31
        const int tp = g >> 1, bh = g & 1;   // t' 0..15, batch half
        const int w = tid >> 6;              // wave 0..15
        const int j = w >> 2;                // pre j-chunk (gate>>8), constant per wave
        float bias[4];
        bf16x8 wv4[4];
#pragma unroll
        for (int tm = 0; tm < 4; tm++) {
            const int tile = w * 4 + tm;     // 16-gate tile 0..63
            bias[tm] = b0s[tile * 16 + col];
            wv4[tm] = *(const bf16x8*)&wih0f[((size_t)tile * 64 + lane) * 8];
        }
        const u16* Ab = xpad8 + ((size_t)L * CH + tp) * BATCH * 8;
#pragma unroll 1
        for (int bt = 0; bt < 8; bt++) {
            const int btg = bh * 8 + bt;     // global 16-batch tile
            bf16x8 af = {0, 0, 0, 0, 0, 0, 0, 0};   // K beyond 8 is zero-padded
            if (kgrp == 0) af = *(const bf16x8*)&Ab[(btg * 16 + col) * 8];
            f32x4 acc[4];
#pragma unroll
            for (int tm = 0; tm < 4; tm++) acc[tm] = (f32x4){bias[tm], bias[tm], bias[tm], bias[tm]};
#pragma unroll
            for (int tm = 0; tm < 4; tm++) acc[tm] = MFMA_BF16(af, wv4[tm], acc[tm]);
            // store: batch = btg*16 + kgrp*4 + rr -> (btile = btg*4+kgrp, kb = rr);
            // lane's 4 rr accs are 4 consecutive pre elements -> one 8B store.
#pragma unroll
            for (int tm = 0; tm < 4; tm++) {
                const int ul = ((w & 3) * 4 + tm) * 16 + col;   // u within j-chunk
                const size_t off = ((((size_t)tp * 64 + btg * 4 + kgrp) * 4 + j) << 10) + (ul << 2);
                u32x2 pk;
                pk.x = (unsigned)f2bf(acc[tm][0]) | ((unsigned)f2bf(acc[tm][1]) << 16);
                pk.y = (unsigned)f2bf(acc[tm][2]) | ((unsigned)f2bf(acc[tm][3]) << 16);
                *(u32x2*)&p0w[off] = pk;
            }
        }
        return;
    } else {
        // ---------------- gemm1: pre1(chunk L-2), operand-swapped ----------------
        if (L < 2 || L > NCH + 1) return;
        const int g = bid - GB1;             // 0..63
        const int tp = g >> 2, j = g & 3;    // t' 0..15, j-chunk 0..3
        const int w = tid >> 6;              // wave = 16-gate tile within j
        const int gt = j * 16 + w;           // global 16-gate tile
        const float bias = b1s[gt * 16 + col];
        bf16x8 wv8[8];                       // 32 VGPRs resident weights
#pragma unroll
        for (int kk = 0; kk < 8; kk++)
            wv8[kk] = *(const bf16x8*)&wih1f[((size_t)(gt * 8 + kk) * 64 + lane) * 8];
#pragma unroll 1
        for (int bt = 0; bt < 16; bt++) {
            f32x4 acc = (f32x4){bias, bias, bias, bias};
#pragma unroll
            for (int kk = 0; kk < 8; kk++) {
                bf16x8 a_ = *(const bf16x8*)&h0r[((size_t)tp * BATCH + bt * 16 + col) * HID + kk * 32 + kgrp * 8];
                acc = MFMA_BF16(a_, wv8[kk], acc);
            }
            const int ul = w * 16 + col;     // u within j-chunk
            const size_t off = ((((size_t)tp * 64 + bt * 4 + kgrp) * 4 + j) << 10) + (ul << 2);
            u32x2 pk;
            pk.x = (unsigned)f2bf(acc[0]) | ((unsigned)f2bf(acc[1]) << 16);
            pk.y = (unsigned)f2bf(acc[2]) | ((unsigned)f2bf(acc[3]) << 16);
            *(u32x2*)&p1w[off] = pk;
        }
        return;
    }
}

// ---------------------------------------------------------------------------
// head: y = sigmoid(relu(h_last) @ Wh^T + bh)
// ---------------------------------------------------------------------------
__global__ void head_kernel(const i8* __restrict__ hs1,
                            const float* __restrict__ Wh, const float* __restrict__ bh,
                            float* __restrict__ y) {
    int b = blockIdx.x;
    int l = threadIdx.x;
    const float inv127 = 1.f / 127.f;
    float hr[4];
#pragma unroll
    for (int i = 0; i < 4; ++i) hr[i] = fmaxf((float)hs1[b * HID + l + 64 * i] * inv127, 0.f);
    for (int o = 0; o < 3; ++o) {
        float s = 0.f;
#pragma unroll
        for (int i = 0; i < 4; ++i) s += hr[i] * Wh[o * HID + l + 64 * i];
        for (int off = 32; off > 0; off >>= 1) s += __shfl_down(s, off, 64);
        if (l == 0) y[b * 3 + o] = 1.f / (1.f + exp2_(-(s + bh[o]) * LOG2E));
    }
}

extern "C" void kernel_launch(void* const* d_in, const int* in_sizes, int n_in,
                              void* d_out, int out_size, void* d_ws, size_t ws_size,
                              hipStream_t stream) {
    const float* x    = (const float*)d_in[0];
    const float* Wih0 = (const float*)d_in[1];
    const float* Whh0 = (const float*)d_in[2];
    const float* bih0 = (const float*)d_in[3];
    const float* bhh0 = (const float*)d_in[4];
    const float* Wih1 = (const float*)d_in[5];
    const float* Whh1 = (const float*)d_in[6];
    const float* bih1 = (const float*)d_in[7];
    const float* bhh1 = (const float*)d_in[8];
    const float* Wh   = (const float*)d_in[9];
    const float* bh   = (const float*)d_in[10];

    char* ws = (char*)d_ws;
    i8*    wi80  = (i8*)(ws);                            // 256 KB
    i8*    wi81  = (i8*)(ws + ((size_t)256 << 10));      // 256 KB
    u16*   wih1f = (u16*)(ws + ((size_t)512 << 10));     // 512 KB
    u16*   wih0f = (u16*)(ws + ((size_t)1024 << 10));    // 64 KB
    float* qs0   = (float*)(ws + ((size_t)1088 << 10));
    float* dq0s  = (float*)(ws + ((size_t)1092 << 10));
    float* qs1   = (float*)(ws + ((size_t)1096 << 10));
    float* dq1s  = (float*)(ws + ((size_t)1100 << 10));
    float* b0s   = (float*)(ws + ((size_t)1104 << 10));
    float* b1s   = (float*)(ws + ((size_t)1108 << 10));
    i8*    hs0   = (i8*)(ws + ((size_t)1112 << 10));     // 64 KB
    i8*    hs1   = (i8*)(ws + ((size_t)1176 << 10));     // 64 KB
    float* cs0   = (float*)(ws + ((size_t)1240 << 10));  // 256 KB
    float* cs1   = (float*)(ws + ((size_t)1496 << 10));  // 256 KB
    u16*   xpad  = (u16*)(ws + ((size_t)1752 << 10));    // 2 MB  [tok][8] bf16
    u16*   h0c   = (u16*)(ws + ((size_t)3800 << 10));    // 2 x 2 MB (chunk parity)
    u16*   pre0  = (u16*)(ws + ((size_t)7896 << 10));    // 2 x 8 MB (chunk parity)
    u16*   pre1  = (u16*)(ws + ((size_t)24280 << 10));   // 2 x 8 MB -> total ~39.7 MB
    const size_t PRE_ELE = (size_t)CH * BATCH * NG;      // 4 Mi elements (8 MB)
    const size_t H0C_ELE = (size_t)CH * BATCH * HID;     // 1 Mi elements (2 MB)

    prep_a<<<4, 256, 0, stream>>>(Whh0, Whh1, bih0, bhh0, bih1, bhh1,
                                  qs0, dq0s, qs1, dq1s, b0s, b1s);
    prep_b<<<1024, 256, 0, stream>>>(x, Wih0, Whh0, Wih1, Whh1, qs0, qs1,
                                     wi80, wi81, wih1f, wih0f, hs0, hs1, cs0, cs1, xpad);
    // pipeline: gemm0(c=L) | rec0(c=L-1) | gemm1(c=L-2) | rec1(c=L-3)
    for (int L = 0; L <= NCH + 2; L++) {
        const size_t pA = (size_t)(L & 1), pB = pA ^ 1;
        stage_fused<<<NBLK, 1024, 0, stream>>>(L, xpad, wih0f, b0s, wih1f, b1s,
            pre0 + pA * PRE_ELE,        // gemm0 writes chunk L      (parity L)
            pre0 + pB * PRE_ELE,        // rec0 reads chunk L-1      (parity L-1)
            h0c  + pB * H0C_ELE,        // rec0 writes chunk L-1
            h0c  + pA * H0C_ELE,        // gemm1 reads chunk L-2     (parity L)
            pre1 + pA * PRE_ELE,        // gemm1 writes chunk L-2
            pre1 + pB * PRE_ELE,        // rec1 reads chunk L-3      (parity L-1)
            wi80, wi81, dq0s, dq1s, hs0, hs1, cs0, cs1);
    }
    head_kernel<<<BATCH, 64, 0, stream>>>(hs1, Wh, bh, (float*)d_out);
}

// Round 4
// 745.632 us; speedup vs baseline: 3.1184x; 2.6677x over previous
//
#include <hip/hip_runtime.h>
#include <hip/hip_bf16.h>

typedef unsigned short u16;
typedef signed char i8;
typedef __attribute__((ext_vector_type(4))) float f32x4;
typedef __attribute__((ext_vector_type(4))) int i32x4;
typedef __attribute__((ext_vector_type(8))) short bf16x8;
typedef __attribute__((ext_vector_type(2))) unsigned int u32x2;

#define HID 256
#define NG 1024
#define TSTEPS 512
#define BATCH 256
#define CH 16          // steps per chunk
#define NCH 32         // chunks (CH*NCH = 512)
#define BB 4           // batch rows per rec block (1 cell/lane via A-row duplication)
#define HSTR 288       // h_lds row stride bytes
#define LOG2E 1.4426950408889634f
#define PRE_TSTR 262144   // per-t' element stride in pre: 64 btiles * 4 j * 1024 (u*4+kb)
#define H0C_TSTR 65536    // per-t element stride in h0c frag layout [kk][bt][kgrp][col][e]

// fused-stage block roles
#define GB0 128        // gemm0 blocks [128,160)
#define GB1 160        // gemm1 blocks [160,224)
#define NBLK 224

#define MFMA_BF16(a, b, c) __builtin_amdgcn_mfma_f32_16x16x32_bf16((a), (b), (c), 0, 0, 0)
#define MFMA_I8(a, b, c)   __builtin_amdgcn_mfma_i32_16x16x64_i8((a), (b), (c), 0, 0, 0)

__device__ __forceinline__ float rcpf_(float x) {
#if __has_builtin(__builtin_amdgcn_rcpf)
    return __builtin_amdgcn_rcpf(x);
#else
    return 1.f / x;
#endif
}
__device__ __forceinline__ float exp2_(float x) {
#if __has_builtin(__builtin_amdgcn_exp2f)
    return __builtin_amdgcn_exp2f(x);
#else
    return exp2f(x);
#endif
}
__device__ __forceinline__ float sigm2(float y) { return rcpf_(1.f + exp2_(-y)); }
__device__ __forceinline__ float tanh2(float y2) { return fmaf(-2.f, rcpf_(exp2_(y2) + 1.f), 1.f); }
__device__ __forceinline__ u16 f2bf(float v){ __hip_bfloat16 h=__float2bfloat16(v); return __builtin_bit_cast(u16,h); }
__device__ __forceinline__ float bf2f(u16 u){ unsigned x=((unsigned)u)<<16; return __builtin_bit_cast(float,x); }

// ---------------------------------------------------------------------------
// prep_a: per-gate-row i8 scales for Whh0/Whh1; log2e folded into dequant
// scales and biases. (unchanged)
// ---------------------------------------------------------------------------
__global__ void prep_a(const float* __restrict__ Whh0, const float* __restrict__ Whh1,
                       const float* __restrict__ bih0, const float* __restrict__ bhh0,
                       const float* __restrict__ bih1, const float* __restrict__ bhh1,
                       float* __restrict__ qs0, float* __restrict__ dq0s,
                       float* __restrict__ qs1, float* __restrict__ dq1s,
                       float* __restrict__ b0s, float* __restrict__ b1s) {
    int r = blockIdx.x * blockDim.x + threadIdx.x;
    if (r >= NG) return;
    float m0 = 1e-20f, m1 = 1e-20f;
    for (int k = 0; k < HID; k++) {
        m0 = fmaxf(m0, fabsf(Whh0[r * HID + k]));
        m1 = fmaxf(m1, fabsf(Whh1[r * HID + k]));
    }
    qs0[r] = 127.f / m0;   dq0s[r] = m0 / 16129.f * LOG2E;
    qs1[r] = 127.f / m1;   dq1s[r] = m1 / 16129.f * LOG2E;
    b0s[r] = (bih0[r] + bhh0[r]) * LOG2E;
    b1s[r] = (bih1[r] + bhh1[r]) * LOG2E;
}

// ---------------------------------------------------------------------------
// prep_b: i8 frag packs for Whh0/Whh1; bf16 Wih1 frags (x LOG2E); bf16 Wih0
// frags (x LOG2E, K pad 5->32); x padded to 8 bf16/token; zeroed states.
// (unchanged)
// ---------------------------------------------------------------------------
__global__ void prep_b(const float* __restrict__ x,
    const float* __restrict__ Wih0, const float* __restrict__ Whh0,
    const float* __restrict__ Wih1, const float* __restrict__ Whh1,
    const float* __restrict__ qs0, const float* __restrict__ qs1,
    i8* __restrict__ wi80, i8* __restrict__ wi81,
    u16* __restrict__ wih1f, u16* __restrict__ wih0f,
    i8* __restrict__ hs0, i8* __restrict__ hs1,
    float* __restrict__ cs0, float* __restrict__ cs1, u16* __restrict__ xpad)
{
    const int stride = gridDim.x * blockDim.x;
    const int tid = blockIdx.x * blockDim.x + threadIdx.x;
    for (int i = tid; i < NG * HID; i += stride) {   // i8 packs (recurrent)
        int e = i & 15, l = (i >> 4) & 63, kc = (i >> 10) & 3, gt = i >> 12;
        int row = 16 * gt + (l & 15);
        int k = kc * 64 + (l >> 4) * 16 + e;
        float q0 = __builtin_rintf(Whh0[row * HID + k] * qs0[row]);
        float q1 = __builtin_rintf(Whh1[row * HID + k] * qs1[row]);
        wi80[i] = (i8)fminf(fmaxf(q0, -127.f), 127.f);
        wi81[i] = (i8)fminf(fmaxf(q1, -127.f), 127.f);
    }
    for (int i = tid; i < NG * HID; i += stride) {   // Wih1 bf16 frags, scaled
        int gt = i >> 12, kk = (i >> 9) & 7, l = (i >> 3) & 63, e = i & 7;
        wih1f[i] = f2bf(Wih1[(16 * gt + (l & 15)) * HID + kk * 32 + (l >> 4) * 8 + e] * LOG2E);
    }
    for (int i = tid; i < 32768; i += stride) {      // Wih0 bf16 frags, scaled
        int gt = i >> 9, l = (i >> 3) & 63, e = i & 7;
        int k = (l >> 4) * 8 + e;
        wih0f[i] = (k < 5) ? f2bf(Wih0[(16 * gt + (l & 15)) * 5 + k] * LOG2E) : (u16)0;
    }
    for (int i = tid; i < TSTEPS * BATCH * 8; i += stride) {  // x padded to 8, token-major
        int tok = i >> 3, k = i & 7, t = tok >> 8, b = tok & 255;
        xpad[i] = (k < 5) ? f2bf(x[((size_t)b * TSTEPS + t) * 5 + k]) : (u16)0;
    }
    for (int i = tid; i < BATCH * HID; i += stride) { hs0[i] = 0; hs1[i] = 0; cs0[i] = 0.f; cs1[i] = 0.f; }
}

// ---------------------------------------------------------------------------
// stage_fused(L): four pipeline roles on disjoint blocks (gemms overlap recs):
//   blocks [0,64):    rec layer0, chunk L-1   (reads pre0, writes h0c)
//   blocks [64,128):  rec layer1, chunk L-3   (reads pre1)
//   blocks [128,160): gemm0: pre0(chunk L)   = log2e*(Wih0 x + b0)
//   blocks [160,224): gemm1: pre1(chunk L-2) = log2e*(Wih1 h0 + b1)
//
// R3 POST-MORTEM FIX: the residual 63us gate was gemm1's A-LOAD gather: old
// h0c layout [t][b][u] made each bf16x8 load a 16-segment x 64B gather
// (col strides 512B); 2048 load-instrs/CU x 16 segs ~ 33K transactions/CU
// ~ 30-50us on gemm1 CUs. h0c is now stored in gemm1's exact fragment order
//   h0c[t][kk][bt][kgrp][col][e]  (e=u&7 contiguous)
// so each gemm1 af load is ONE 1024B coalesced burst (64 lanes x 16B).
// Producer side (rec0 per-lane store) goes 4x32B -> 8x16B segments -- cheap.
// Pure permutation: bit-identical values.
// ---------------------------------------------------------------------------
__global__ __launch_bounds__(1024) __attribute__((amdgpu_waves_per_eu(4, 4)))
void stage_fused(int L,
    const u16* __restrict__ xpad8, const u16* __restrict__ wih0f, const float* __restrict__ b0s,
    const u16* __restrict__ wih1f, const float* __restrict__ b1s,
    u16* __restrict__ p0w, const u16* __restrict__ p0r,
    u16* __restrict__ h0w, const u16* __restrict__ h0r,
    u16* __restrict__ p1w, const u16* __restrict__ p1r,
    const i8* __restrict__ wi80, const i8* __restrict__ wi81,
    const float* __restrict__ dq0s, const float* __restrict__ dq1s,
    i8* __restrict__ hs0, i8* __restrict__ hs1,
    float* __restrict__ cs0, float* __restrict__ cs1)
{
    __shared__ i8 h_lds[2][BB * HSTR];
    const int bid = blockIdx.x;
    const int tid = threadIdx.x, lane = tid & 63;
    const int col = lane & 15, kgrp = lane >> 4;

    if (bid < GB0) {
        // ---------------- recurrent role ----------------
        const int layer = bid >> 6;
        if (layer == 0) { if (L < 1 || L > NCH) return; }
        else            { if (L < 3 || L > NCH + 2) return; }
        const int btile = bid & 63;
        const u16* pre   = layer ? p1r : p0r;
        const i8*  wi8   = layer ? wi81 : wi80;
        const float* dq  = layer ? dq1s : dq0s;
        i8*    h_state   = layer ? hs1 : hs0;
        float* c_state   = layer ? cs1 : cs0;
        const int w = tid >> 6;
        const int b0 = btile * BB;
        const int u = w * 16 + col;          // h-unit this lane owns

        float sc[4];
        i32x4 wv[4][4];                      // 64 VGPRs resident weights
#pragma unroll
        for (int j = 0; j < 4; j++) {
            const int gt = 16 * j + w;
            sc[j] = dq[gt * 16 + col];
#pragma unroll
            for (int kc = 0; kc < 4; kc++)
                wv[j][kc] = ((const i32x4*)wi8)[(gt * 4 + kc) * 64 + lane];
        }
        if (tid < 64 * BB) {
            const int rrow = tid >> 6, cc = (tid & 63) * 4;
            *(int*)&h_lds[0][rrow * HSTR + cc] = *(const int*)&h_state[(b0 + rrow) * HID + cc];
        }
        float c_reg = c_state[(size_t)(b0 + kgrp) * HID + u];

        // pre base for this lane: btile*4096 + u*4 + kgrp   (contiguous per wave)
        const u16* pb = pre + ((size_t)btile << 12) + (u << 2) + kgrp;
        u16 pvA[4], pvB[4];
#pragma unroll
        for (int j = 0; j < 4; j++) pvA[j] = pb[j << 10];
        // h0c store base in frag layout [t][kk=u>>5][bt=btile>>2][kgrp_g=(u>>3)&3][b&15][e=u&7]
        const size_t h0base = ((((size_t)(w >> 1) * 16 + (btile >> 2)) * 4
                               + ((w & 1) * 2 + (col >> 3))) * 16
                              + ((btile & 3) * 4 + kgrp)) * 8 + (col & 7);
        __syncthreads();

#define REC_STEP(T, CUR, PVC, PVN) do {                                             \
        _Pragma("unroll")                                                           \
        for (int j = 0; j < 4; j++)                                                 \
            asm volatile("" : "+v"(wv[j][0]), "+v"(wv[j][1]),                       \
                              "+v"(wv[j][2]), "+v"(wv[j][3]));                      \
        i32x4 acc[4];                                                               \
        _Pragma("unroll")                                                           \
        for (int j = 0; j < 4; j++) acc[j] = (i32x4){0, 0, 0, 0};                   \
        _Pragma("unroll")                                                           \
        for (int kc = 0; kc < 4; kc++) {                                            \
            i32x4 a_ = *(const i32x4*)&h_lds[CUR][(col >> 2) * HSTR + kc * 64 + kgrp * 16]; \
            _Pragma("unroll")                                                       \
            for (int j = 0; j < 4; j++) acc[j] = MFMA_I8(a_, wv[j][kc], acc[j]);    \
        }                                                                           \
        const int tn_ = ((T) + 1 < CH) ? (T) + 1 : (T);                             \
        _Pragma("unroll")                                                           \
        for (int j = 0; j < 4; j++) PVN[j] = pb[(size_t)tn_ * PRE_TSTR + (j << 10)];\
        const float yi = fmaf((float)acc[0][0], sc[0], bf2f(PVC[0]));               \
        const float yf = fmaf((float)acc[1][0], sc[1], bf2f(PVC[1]));               \
        const float yg = fmaf((float)acc[2][0], sc[2], bf2f(PVC[2]));               \
        const float yo = fmaf((float)acc[3][0], sc[3], bf2f(PVC[3]));               \
        const float iv = sigm2(yi), fv = sigm2(yf), ov = sigm2(yo);                 \
        const float gv = tanh2(yg + yg);                                            \
        const float cn = fmaf(fv, c_reg, iv * gv);                                  \
        c_reg = cn;                                                                 \
        const float hv = ov * tanh2(cn * (2.f * LOG2E));                            \
        h_lds[(CUR) ^ 1][kgrp * HSTR + u] = (i8)__float2int_rn(hv * 127.f);         \
        if (layer == 0)                                                             \
            h0w[h0base + (size_t)(T) * H0C_TSTR] = f2bf(hv);                        \
        asm volatile("s_waitcnt lgkmcnt(0)" ::: "memory");                          \
        __builtin_amdgcn_s_barrier();                                               \
        __builtin_amdgcn_sched_barrier(0);                                          \
    } while (0)

#pragma unroll 1
        for (int t2 = 0; t2 < CH; t2 += 2) {
            REC_STEP(t2,     0, pvA, pvB);
            REC_STEP(t2 + 1, 1, pvB, pvA);
        }
#undef REC_STEP

        c_state[(size_t)(b0 + kgrp) * HID + u] = c_reg;
        if (tid < 64 * BB) {
            const int rrow = tid >> 6, cc = (tid & 63) * 4;
            *(int*)&h_state[(b0 + rrow) * HID + cc] = *(const int*)&h_lds[0][rrow * HSTR + cc];
        }
        return;
    } else if (bid < GB1) {
        // ---------------- gemm0: pre0(chunk L), operand-swapped ----------------
        if (L >= NCH) return;
        const int g = bid - GB0;             // 0..31
        const int tp = g >> 1, bh = g & 1;   // t' 0..15, batch half
        const int w = tid >> 6;              // wave 0..15
        const int j = w >> 2;                // pre j-chunk (gate>>8), constant per wave
        float bias[4];
        bf16x8 wv4[4];
#pragma unroll
        for (int tm = 0; tm < 4; tm++) {
            const int tile = w * 4 + tm;     // 16-gate tile 0..63
            bias[tm] = b0s[tile * 16 + col];
            wv4[tm] = *(const bf16x8*)&wih0f[((size_t)tile * 64 + lane) * 8];
        }
        const u16* Ab = xpad8 + ((size_t)L * CH + tp) * BATCH * 8;
#pragma unroll 1
        for (int bt = 0; bt < 8; bt++) {
            const int btg = bh * 8 + bt;     // global 16-batch tile
            bf16x8 af = {0, 0, 0, 0, 0, 0, 0, 0};   // K beyond 8 is zero-padded
            if (kgrp == 0) af = *(const bf16x8*)&Ab[(btg * 16 + col) * 8];
            f32x4 acc[4];
#pragma unroll
            for (int tm = 0; tm < 4; tm++) acc[tm] = (f32x4){bias[tm], bias[tm], bias[tm], bias[tm]};
#pragma unroll
            for (int tm = 0; tm < 4; tm++) acc[tm] = MFMA_BF16(af, wv4[tm], acc[tm]);
            // store: batch = btg*16 + kgrp*4 + rr -> (btile = btg*4+kgrp, kb = rr);
            // lane's 4 rr accs are 4 consecutive pre elements -> one 8B store.
#pragma unroll
            for (int tm = 0; tm < 4; tm++) {
                const int ul = ((w & 3) * 4 + tm) * 16 + col;   // u within j-chunk
                const size_t off = ((((size_t)tp * 64 + btg * 4 + kgrp) * 4 + j) << 10) + (ul << 2);
                u32x2 pk;
                pk.x = (unsigned)f2bf(acc[tm][0]) | ((unsigned)f2bf(acc[tm][1]) << 16);
                pk.y = (unsigned)f2bf(acc[tm][2]) | ((unsigned)f2bf(acc[tm][3]) << 16);
                *(u32x2*)&p0w[off] = pk;
            }
        }
        return;
    } else {
        // ---------------- gemm1: pre1(chunk L-2), operand-swapped, frag-layout A ----------------
        if (L < 2 || L > NCH + 1) return;
        const int g = bid - GB1;             // 0..63
        const int tp = g >> 2, j = g & 3;    // t' 0..15, j-chunk 0..3
        const int w = tid >> 6;              // wave = 16-gate tile within j
        const int gt = j * 16 + w;           // global 16-gate tile
        const float bias = b1s[gt * 16 + col];
        bf16x8 wv8[8];                       // 32 VGPRs resident weights
#pragma unroll
        for (int kk = 0; kk < 8; kk++)
            wv8[kk] = *(const bf16x8*)&wih1f[((size_t)(gt * 8 + kk) * 64 + lane) * 8];
        // A base: h0r[t=tp][kk][bt][lane]*8 -- per (kk,bt) the wave reads 1024B coalesced
        const u16* A0 = h0r + (size_t)tp * H0C_TSTR + (size_t)lane * 8;
#pragma unroll 1
        for (int bt = 0; bt < 16; bt++) {
            bf16x8 a8[8];
#pragma unroll
            for (int kk = 0; kk < 8; kk++)
                a8[kk] = *(const bf16x8*)&A0[((size_t)kk * 16 + bt) * 512];
            f32x4 acc = (f32x4){bias, bias, bias, bias};
#pragma unroll
            for (int kk = 0; kk < 8; kk++)
                acc = MFMA_BF16(a8[kk], wv8[kk], acc);
            const int ul = w * 16 + col;     // u within j-chunk
            const size_t off = ((((size_t)tp * 64 + bt * 4 + kgrp) * 4 + j) << 10) + (ul << 2);
            u32x2 pk;
            pk.x = (unsigned)f2bf(acc[0]) | ((unsigned)f2bf(acc[1]) << 16);
            pk.y = (unsigned)f2bf(acc[2]) | ((unsigned)f2bf(acc[3]) << 16);
            *(u32x2*)&p1w[off] = pk;
        }
        return;
    }
}

// ---------------------------------------------------------------------------
// head: y = sigmoid(relu(h_last) @ Wh^T + bh)
// ---------------------------------------------------------------------------
__global__ void head_kernel(const i8* __restrict__ hs1,
                            const float* __restrict__ Wh, const float* __restrict__ bh,
                            float* __restrict__ y) {
    int b = blockIdx.x;
    int l = threadIdx.x;
    const float inv127 = 1.f / 127.f;
    float hr[4];
#pragma unroll
    for (int i = 0; i < 4; ++i) hr[i] = fmaxf((float)hs1[b * HID + l + 64 * i] * inv127, 0.f);
    for (int o = 0; o < 3; ++o) {
        float s = 0.f;
#pragma unroll
        for (int i = 0; i < 4; ++i) s += hr[i] * Wh[o * HID + l + 64 * i];
        for (int off = 32; off > 0; off >>= 1) s += __shfl_down(s, off, 64);
        if (l == 0) y[b * 3 + o] = 1.f / (1.f + exp2_(-(s + bh[o]) * LOG2E));
    }
}

extern "C" void kernel_launch(void* const* d_in, const int* in_sizes, int n_in,
                              void* d_out, int out_size, void* d_ws, size_t ws_size,
                              hipStream_t stream) {
    const float* x    = (const float*)d_in[0];
    const float* Wih0 = (const float*)d_in[1];
    const float* Whh0 = (const float*)d_in[2];
    const float* bih0 = (const float*)d_in[3];
    const float* bhh0 = (const float*)d_in[4];
    const float* Wih1 = (const float*)d_in[5];
    const float* Whh1 = (const float*)d_in[6];
    const float* bih1 = (const float*)d_in[7];
    const float* bhh1 = (const float*)d_in[8];
    const float* Wh   = (const float*)d_in[9];
    const float* bh   = (const float*)d_in[10];

    char* ws = (char*)d_ws;
    i8*    wi80  = (i8*)(ws);                            // 256 KB
    i8*    wi81  = (i8*)(ws + ((size_t)256 << 10));      // 256 KB
    u16*   wih1f = (u16*)(ws + ((size_t)512 << 10));     // 512 KB
    u16*   wih0f = (u16*)(ws + ((size_t)1024 << 10));    // 64 KB
    float* qs0   = (float*)(ws + ((size_t)1088 << 10));
    float* dq0s  = (float*)(ws + ((size_t)1092 << 10));
    float* qs1   = (float*)(ws + ((size_t)1096 << 10));
    float* dq1s  = (float*)(ws + ((size_t)1100 << 10));
    float* b0s   = (float*)(ws + ((size_t)1104 << 10));
    float* b1s   = (float*)(ws + ((size_t)1108 << 10));
    i8*    hs0   = (i8*)(ws + ((size_t)1112 << 10));     // 64 KB
    i8*    hs1   = (i8*)(ws + ((size_t)1176 << 10));     // 64 KB
    float* cs0   = (float*)(ws + ((size_t)1240 << 10));  // 256 KB
    float* cs1   = (float*)(ws + ((size_t)1496 << 10));  // 256 KB
    u16*   xpad  = (u16*)(ws + ((size_t)1752 << 10));    // 2 MB  [tok][8] bf16
    u16*   h0c   = (u16*)(ws + ((size_t)3800 << 10));    // 2 x 2 MB (chunk parity)
    u16*   pre0  = (u16*)(ws + ((size_t)7896 << 10));    // 2 x 8 MB (chunk parity)
    u16*   pre1  = (u16*)(ws + ((size_t)24280 << 10));   // 2 x 8 MB -> total ~39.7 MB
    const size_t PRE_ELE = (size_t)CH * BATCH * NG;      // 4 Mi elements (8 MB)
    const size_t H0C_ELE = (size_t)CH * BATCH * HID;     // 1 Mi elements (2 MB)

    prep_a<<<4, 256, 0, stream>>>(Whh0, Whh1, bih0, bhh0, bih1, bhh1,
                                  qs0, dq0s, qs1, dq1s, b0s, b1s);
    prep_b<<<1024, 256, 0, stream>>>(x, Wih0, Whh0, Wih1, Whh1, qs0, qs1,
                                     wi80, wi81, wih1f, wih0f, hs0, hs1, cs0, cs1, xpad);
    // pipeline: gemm0(c=L) | rec0(c=L-1) | gemm1(c=L-2) | rec1(c=L-3)
    for (int L = 0; L <= NCH + 2; L++) {
        const size_t pA = (size_t)(L & 1), pB = pA ^ 1;
        stage_fused<<<NBLK, 1024, 0, stream>>>(L, xpad, wih0f, b0s, wih1f, b1s,
            pre0 + pA * PRE_ELE,        // gemm0 writes chunk L      (parity L)
            pre0 + pB * PRE_ELE,        // rec0 reads chunk L-1      (parity L-1)
            h0c  + pB * H0C_ELE,        // rec0 writes chunk L-1
            h0c  + pA * H0C_ELE,        // gemm1 reads chunk L-2     (parity L)
            pre1 + pA * PRE_ELE,        // gemm1 writes chunk L-2
            pre1 + pB * PRE_ELE,        // rec1 reads chunk L-3      (parity L-1)
            wi80, wi81, dq0s, dq1s, hs0, hs1, cs0, cs1);
    }
    head_kernel<<<BATCH, 64, 0, stream>>>(hs1, Wh, bh, (float*)d_out);
}